// Round 1
// baseline (749.891 us; speedup 1.0000x reference)
//
#include <hip/hip_runtime.h>
#include <hip/hip_bf16.h>

// AUGRU dynamic RNN: B=1024, T=512, D=128.
// 64 blocks x 512 threads (8 waves); block owns 16 batch rows for all T.
// Round-1 restructure vs previous best:
//  * Gate columns re-mapped: wave w computes gate cols {ccol, 128+ccol}
//    (ccol = 16*wid + lane&15) so the u-gate for col ccol lands in the SAME
//    lane that owns h[row][ccol]. u' = (1-a)*u stays in registers -> the
//    f32 'ub' LDS round-trip is deleted.
//  * Master h kept ONLY in registers (h_reg[4], f32); r*h uses h_reg
//    directly -> f32 'hf' LDS array and act-phase h reads deleted.
//  * Act phase now wave-uniform (no wid<4 divergence); biases folded into
//    the exp2 argument; (1-a) hoisted per step.
//  * cand x-part MFMAs moved before barrier 1 (phase-2 chain is only the
//    4 rh-part MFMAs + tanh + update).
// MFMA count/fragment layouts/barrier structure unchanged from verified kernel.

#define Bn 1024
#define Tn 512
#define Dn 128

typedef __attribute__((ext_vector_type(8))) short short8;   // 8 bf16 (4 VGPR)
typedef __attribute__((ext_vector_type(4))) short short4v;
typedef __attribute__((ext_vector_type(4))) float f32x4;

#define BS 136   // bf16 LDS row stride (shorts): 272 B = 17*16B
#define NLOG2E (-1.4426950408889634f)

__device__ __forceinline__ short f2bf(float f) {
    __hip_bfloat16 h = __float2bfloat16(f);   // RNE
    return __builtin_bit_cast(short, h);
}

#define MFMA(a, b, c) __builtin_amdgcn_mfma_f32_16x16x32_bf16((a), (b), (c), 0, 0, 0)

__launch_bounds__(512, 2)
__global__ void augru_kernel(const float* __restrict__ X,    // [B,T,D]
                             const float* __restrict__ ATT,  // [B,T,1]
                             const float* __restrict__ GK,   // [256,256]
                             const float* __restrict__ GB,   // [256]
                             const float* __restrict__ CK,   // [256,128]
                             const float* __restrict__ CB,   // [128]
                             const int*   __restrict__ SL,   // [B,1]
                             float* __restrict__ OUT) {      // [B,T,D]
    __shared__ short hb [16 * BS];      // h  (bf16 mirror, A-frag source)
    __shared__ short rhb[16 * BS];      // r*h (bf16, A-frag source)
    __shared__ short xb [2][16 * BS];   // x tile, double-buffered
    __shared__ float abuf[2][16];
    __shared__ int   lenbuf[16];

    const int tid  = threadIdx.x;
    const int wid  = tid >> 6;          // 0..7
    const int lane = tid & 63;
    const int lm   = lane & 15;         // MFMA m / n / col index
    const int q    = lane >> 4;         // quad
    const int b0   = blockIdx.x * 16;
    const int ccol = 16 * wid + lm;     // this wave's owned column (r / u-128 / cand / h)

    // ---------- preload weight B-frags (B[k][n]: n=lane&15, k=q*8+j) ----------
    // gate col group 0 = ccol (r), group 1 = 128+ccol (u); cand col = ccol.
    short8 fgx0[4], fgx1[4], fgh0[4], fgh1[4], fcx[4], fch[4];
#pragma unroll
    for (int ks = 0; ks < 4; ++ks) {
        short8 v0, v1, v2, v3, v4, v5;
#pragma unroll
        for (int j = 0; j < 8; ++j) {
            const int k = ks * 32 + q * 8 + j;
            v0[j] = f2bf(GK[k * 256 + ccol]);               // x-part, r col
            v1[j] = f2bf(GK[k * 256 + 128 + ccol]);         // x-part, u col
            v2[j] = f2bf(GK[(128 + k) * 256 + ccol]);       // h-part, r col
            v3[j] = f2bf(GK[(128 + k) * 256 + 128 + ccol]); // h-part, u col
            v4[j] = f2bf(CK[k * 128 + ccol]);               // cand x-part
            v5[j] = f2bf(CK[(128 + k) * 128 + ccol]);       // cand rh-part
        }
        fgx0[ks] = v0; fgx1[ks] = v1; fgh0[ks] = v2; fgh1[ks] = v3;
        fcx[ks] = v4;  fch[ks] = v5;
    }
    // biases folded into exp2 argument: sigmoid(g+b) = rcp(1 + 2^(g*(-log2e) + b*(-log2e)))
    const float bp0 = GB[ccol] * NLOG2E;
    const float bp1 = GB[128 + ccol] * NLOG2E;
    const float cbp = CB[ccol] * (2.0f * NLOG2E);   // tanh(c+cb): 2^((c)*(-2log2e) + cb*(-2log2e))

    // ---------- init LDS state ----------
    for (int i = tid; i < 16 * BS; i += 512) hb[i] = 0;
    if (tid < 16) {
        lenbuf[tid]  = SL[b0 + tid];
        abuf[0][tid] = ATT[(size_t)(b0 + tid) * Tn];
    }
    const int prow = tid >> 5;            // x staging: row 0..15
    const int pcol = (tid & 31) * 4;      // 4 consecutive floats
    {   // stage x for t=0
        float4 v = *(const float4*)(X + ((size_t)(b0 + prow) * Tn) * Dn + pcol);
        short4v s; s[0] = f2bf(v.x); s[1] = f2bf(v.y); s[2] = f2bf(v.z); s[3] = f2bf(v.w);
        *(short4v*)&xb[0][prow * BS + pcol] = s;
    }
    __syncthreads();

    int len_i[4];
    float h_reg[4] = {0.f, 0.f, 0.f, 0.f};   // master h (f32): rows q*4+i, col ccol
#pragma unroll
    for (int i = 0; i < 4; ++i) len_i[i] = lenbuf[q * 4 + i];

    // ---------- time loop ----------
    for (int t = 0; t < Tn; ++t) {
        const int cur = t & 1, nxt = cur ^ 1;

        // prefetch x/att for t+1 (consumed at bottom of this step)
        const int tp = (t + 1 < Tn) ? t + 1 : Tn - 1;
        float4 xpre = *(const float4*)(X + ((size_t)(b0 + prow) * Tn + tp) * Dn + pcol);
        float  apre = (tid < 16) ? ATT[(size_t)(b0 + tid) * Tn + tp] : 0.0f;

        // hoist (1 - a) per owned row
        float am[4];
#pragma unroll
        for (int i = 0; i < 4; ++i) am[i] = 1.0f - abuf[cur][q * 4 + i];

        // A-frags: A[m=lane&15][k=q*8+j]
        short8 ax[4], ah[4];
#pragma unroll
        for (int ks = 0; ks < 4; ++ks) {
            ax[ks] = *(const short8*)&xb[cur][lm * BS + ks * 32 + q * 8];
            ah[ks] = *(const short8*)&hb[lm * BS + ks * 32 + q * 8];
        }

        // gate r-col (g0), gate u-col (g1), cand x-part (cc)
        f32x4 g0 = {0.f,0.f,0.f,0.f}, g1 = {0.f,0.f,0.f,0.f}, cc = {0.f,0.f,0.f,0.f};
#pragma unroll
        for (int ks = 0; ks < 4; ++ks) {
            g0 = MFMA(ah[ks], fgh0[ks], g0);
            g1 = MFMA(ah[ks], fgh1[ks], g1);
            g0 = MFMA(ax[ks], fgx0[ks], g0);
            g1 = MFMA(ax[ks], fgx1[ks], g1);
            cc = MFMA(ax[ks], fcx[ks], cc);
        }

        // activations (C/D layout: col=lane&15 -> ccol, row=q*4+i) — wave-uniform
        float up[4];
#pragma unroll
        for (int i = 0; i < 4; ++i) {
            const int row = q * 4 + i;
            const float er = __builtin_amdgcn_exp2f(fmaf(g0[i], NLOG2E, bp0));
            const float r  = __builtin_amdgcn_rcpf(1.0f + er);
            rhb[row * BS + ccol] = f2bf(r * h_reg[i]);      // r*h from register h (f32)
            const float eu = __builtin_amdgcn_exp2f(fmaf(g1[i], NLOG2E, bp1));
            up[i] = am[i] * __builtin_amdgcn_rcpf(1.0f + eu);   // u' stays in regs
        }
        __syncthreads();

        // cand rh-part: cc += (r*h) @ CKh
#pragma unroll
        for (int ks = 0; ks < 4; ++ks) {
            short8 arh = *(const short8*)&rhb[lm * BS + ks * 32 + q * 8];
            cc = MFMA(arh, fch[ks], cc);
        }

        // h update + output
#pragma unroll
        for (int i = 0; i < 4; ++i) {
            const int row = q * 4 + i;
            const float e  = __builtin_amdgcn_exp2f(fmaf(cc[i], 2.0f * NLOG2E, cbp));
            const float cv = fmaf(2.0f, __builtin_amdgcn_rcpf(1.0f + e), -1.0f);
            const float hn = fmaf(up[i], h_reg[i] - cv, cv);   // u'*h + (1-u')*c
            const bool valid = (t < len_i[i]);
            h_reg[i] = valid ? hn : h_reg[i];
            OUT[((size_t)(b0 + row) * Tn + t) * Dn + ccol] = valid ? hn : 0.0f;
            hb[row * BS + ccol] = f2bf(h_reg[i]);
        }

        // stage prefetched x/att into next buffers
        {
            short4v s; s[0] = f2bf(xpre.x); s[1] = f2bf(xpre.y);
                       s[2] = f2bf(xpre.z); s[3] = f2bf(xpre.w);
            *(short4v*)&xb[nxt][prow * BS + pcol] = s;
            if (tid < 16) abuf[nxt][tid] = apre;
        }
        __syncthreads();
    }
}

extern "C" void kernel_launch(void* const* d_in, const int* in_sizes, int n_in,
                              void* d_out, int out_size, void* d_ws, size_t ws_size,
                              hipStream_t stream) {
    (void)in_sizes; (void)n_in; (void)d_ws; (void)ws_size; (void)out_size;
    const float* X   = (const float*)d_in[0];
    const float* ATT = (const float*)d_in[1];
    const float* GK  = (const float*)d_in[2];
    const float* GB  = (const float*)d_in[3];
    const float* CK  = (const float*)d_in[4];
    const float* CB  = (const float*)d_in[5];
    const int*   SL  = (const int*)d_in[6];
    float* OUT = (float*)d_out;

    augru_kernel<<<dim3(Bn / 16), dim3(512), 0, stream>>>(X, ATT, GK, GB, CK, CB, SL, OUT);
}

// Round 2
// 629.917 us; speedup vs baseline: 1.1905x; 1.1905x over previous
//
#include <hip/hip_runtime.h>
#include <hip/hip_bf16.h>

// AUGRU dynamic RNN:  B=1024 batch rows, T=512 steps, D=128.
// One persistent kernel: 64 blocks x 512 threads (8 waves); block owns 16
// batch rows for all T steps. Weights preloaded once as bf16 MFMA B-frags.
// Per step: gate = [x,h]@Wg via mfma_f32_16x16x32_bf16 (waves split N=256),
// sigmoid -> r,u ; cand = [x,r*h]@Wc ; tanh ; h-update. Master h kept f32 in
// LDS; bf16 mirror for A-frags. x tile prefetched one step ahead.
//
// Round-2 change vs verified 630us kernel (ONLY change): in-loop
// __syncthreads() replaced by raw s_barrier + s_waitcnt lgkmcnt(0).
// __syncthreads forces "s_waitcnt vmcnt(0)" before s_barrier, which
// serialized the t+1 x/att prefetch (barrier 1) and the OUT store acks
// (barrier 2) into every step. LDS ordering only needs lgkmcnt; vmcnt now
// floats to the true use point (T4: never drain vmcnt in the main loop).

#define Bn 1024
#define Tn 512
#define Dn 128

typedef __attribute__((ext_vector_type(8))) short short8;   // 8 bf16 (4 VGPR)
typedef __attribute__((ext_vector_type(4))) short short4v;
typedef __attribute__((ext_vector_type(4))) float f32x4;

#define HS 132   // f32 LDS row stride (floats)  : 16x128 + pad
#define BS 136   // bf16 LDS row stride (shorts) : 272 B = 17*16B (aligned, odd 16B stride)

__device__ __forceinline__ short f2bf(float f) {
    __hip_bfloat16 h = __float2bfloat16(f);   // RNE
    return __builtin_bit_cast(short, h);
}
__device__ __forceinline__ float sigmoidf_(float x) {
    float e = __expf(-x);
    return __builtin_amdgcn_rcpf(1.0f + e);
}
__device__ __forceinline__ float tanhf_(float x) {
    float e = __expf(-2.0f * x);
    return 2.0f * __builtin_amdgcn_rcpf(1.0f + e) - 1.0f;
}

// LDS-only barrier: order LDS ops across waves WITHOUT draining vmcnt
// (global stores / prefetch loads keep flying across the barrier).
__device__ __forceinline__ void barrier_lds() {
    __builtin_amdgcn_sched_barrier(0);
    asm volatile("s_waitcnt lgkmcnt(0)" ::: "memory");
    __builtin_amdgcn_s_barrier();
    __builtin_amdgcn_sched_barrier(0);
}

__launch_bounds__(512, 2)
__global__ void augru_kernel(const float* __restrict__ X,    // [B,T,D]
                             const float* __restrict__ ATT,  // [B,T,1]
                             const float* __restrict__ GK,   // [256,256]
                             const float* __restrict__ GB,   // [256]
                             const float* __restrict__ CK,   // [256,128]
                             const float* __restrict__ CB,   // [128]
                             const int*   __restrict__ SL,   // [B,1]
                             float* __restrict__ OUT) {      // [B,T,D]
    __shared__ short hb [16 * BS];      // h  (bf16 mirror, A-frag source)
    __shared__ short rhb[16 * BS];      // r*h (bf16, A-frag source)
    __shared__ short xb [2][16 * BS];   // x tile, double-buffered
    __shared__ float hf [16 * HS];      // master h (f32)
    __shared__ float ub [16 * HS];      // u' = (1-a)*u (f32)
    __shared__ float abuf[2][16];
    __shared__ int   lenbuf[16];

    const int tid  = threadIdx.x;
    const int wid  = tid >> 6;          // 0..7
    const int lane = tid & 63;
    const int lm   = lane & 15;         // MFMA m / n / col index
    const int q    = lane >> 4;         // quad
    const int b0   = blockIdx.x * 16;

    // ---------- preload weight B-frags (B[k][n]: n=lane&15, k=q*8+j) ----------
    short8 fgx[2][4], fgh[2][4], fcx[4], fch[4];
    const int gcolb = 32 * wid + lm;     // gate col base for this wave
    const int ccol  = 16 * wid + lm;     // cand col for this wave
#pragma unroll
    for (int ns = 0; ns < 2; ++ns) {
        const int col = gcolb + 16 * ns;
#pragma unroll
        for (int ks = 0; ks < 4; ++ks) {
            short8 vx, vh;
#pragma unroll
            for (int j = 0; j < 8; ++j) {
                const int k = ks * 32 + q * 8 + j;
                vx[j] = f2bf(GK[k * 256 + col]);           // x-part rows 0..127
                vh[j] = f2bf(GK[(128 + k) * 256 + col]);   // h-part rows 128..255
            }
            fgx[ns][ks] = vx; fgh[ns][ks] = vh;
        }
    }
#pragma unroll
    for (int ks = 0; ks < 4; ++ks) {
        short8 vx, vh;
#pragma unroll
        for (int j = 0; j < 8; ++j) {
            const int k = ks * 32 + q * 8 + j;
            vx[j] = f2bf(CK[k * 128 + ccol]);
            vh[j] = f2bf(CK[(128 + k) * 128 + ccol]);
        }
        fcx[ks] = vx; fch[ks] = vh;
    }
    const float gb0 = GB[gcolb];
    const float gb1 = GB[gcolb + 16];
    const float cb  = CB[ccol];

    // ---------- init LDS state ----------
    for (int i = tid; i < 16 * HS; i += 512) hf[i] = 0.0f;
    for (int i = tid; i < 16 * BS; i += 512) hb[i] = 0;
    if (tid < 16) {
        lenbuf[tid]  = SL[b0 + tid];
        abuf[0][tid] = ATT[(size_t)(b0 + tid) * Tn];
    }
    const int prow = tid >> 5;            // x staging: row 0..15
    const int pcol = (tid & 31) * 4;      // 4 consecutive floats
    {   // stage x for t=0
        float4 v = *(const float4*)(X + ((size_t)(b0 + prow) * Tn + 0) * Dn + pcol);
        short4v s; s[0] = f2bf(v.x); s[1] = f2bf(v.y); s[2] = f2bf(v.z); s[3] = f2bf(v.w);
        *(short4v*)&xb[0][prow * BS + pcol] = s;
    }
    __syncthreads();

    int len_i[4];
#pragma unroll
    for (int i = 0; i < 4; ++i) len_i[i] = lenbuf[q * 4 + i];

    // ---------- time loop ----------
    for (int t = 0; t < Tn; ++t) {
        const int cur = t & 1, nxt = cur ^ 1;

        // prefetch x/att for t+1 (consumed at bottom of this step)
        const int tp = (t + 1 < Tn) ? t + 1 : Tn - 1;
        float4 xpre = *(const float4*)(X + ((size_t)(b0 + prow) * Tn + tp) * Dn + pcol);
        float  apre = (tid < 16) ? ATT[(size_t)(b0 + tid) * Tn + tp] : 0.0f;

        // A-frags: A[m=lane&15][k=q*8+j]
        short8 ax[4], ah[4];
#pragma unroll
        for (int ks = 0; ks < 4; ++ks) {
            ax[ks] = *(const short8*)&xb[cur][lm * BS + ks * 32 + q * 8];
            ah[ks] = *(const short8*)&hb[lm * BS + ks * 32 + q * 8];
        }

        // gate: gi = [x,h] @ GK  (wave covers cols 32*wid .. +32)
        f32x4 g0 = {0.f, 0.f, 0.f, 0.f}, g1 = {0.f, 0.f, 0.f, 0.f};
#pragma unroll
        for (int ks = 0; ks < 4; ++ks) {
            g0 = __builtin_amdgcn_mfma_f32_16x16x32_bf16(ah[ks], fgh[0][ks], g0, 0, 0, 0);
            g1 = __builtin_amdgcn_mfma_f32_16x16x32_bf16(ah[ks], fgh[1][ks], g1, 0, 0, 0);
            g0 = __builtin_amdgcn_mfma_f32_16x16x32_bf16(ax[ks], fgx[0][ks], g0, 0, 0, 0);
            g1 = __builtin_amdgcn_mfma_f32_16x16x32_bf16(ax[ks], fgx[1][ks], g1, 0, 0, 0);
        }

        // activations (C/D layout: col=lane&15, row=q*4+i)
        if (wid < 4) {            // r cols 0..127
#pragma unroll
            for (int ns = 0; ns < 2; ++ns) {
                const int col = 32 * wid + 16 * ns + lm;
                const float bias = ns ? gb1 : gb0;
                const f32x4 gg = ns ? g1 : g0;
#pragma unroll
                for (int i = 0; i < 4; ++i) {
                    const int row = q * 4 + i;
                    const float r = sigmoidf_(gg[i] + bias);
                    rhb[row * BS + col] = f2bf(r * hf[row * HS + col]);
                }
            }
        } else {                  // u cols 128..255
#pragma unroll
            for (int ns = 0; ns < 2; ++ns) {
                const int cu = 32 * (wid - 4) + 16 * ns + lm;
                const float bias = ns ? gb1 : gb0;
                const f32x4 gg = ns ? g1 : g0;
#pragma unroll
                for (int i = 0; i < 4; ++i) {
                    const int row = q * 4 + i;
                    const float u = sigmoidf_(gg[i] + bias);
                    ub[row * HS + cu] = (1.0f - abuf[cur][row]) * u;
                }
            }
        }
        barrier_lds();

        // cand: c = tanh([x, r*h] @ CK + cb)  (wave covers cols 16*wid .. +16)
        f32x4 cc = {0.f, 0.f, 0.f, 0.f};
#pragma unroll
        for (int ks = 0; ks < 4; ++ks) {
            short8 arh = *(const short8*)&rhb[lm * BS + ks * 32 + q * 8];
            cc = __builtin_amdgcn_mfma_f32_16x16x32_bf16(arh, fch[ks], cc, 0, 0, 0);
            cc = __builtin_amdgcn_mfma_f32_16x16x32_bf16(ax[ks], fcx[ks], cc, 0, 0, 0);
        }

        // h update + output (each wave owns cand cols 16*wid..+16, all 16 rows)
#pragma unroll
        for (int i = 0; i < 4; ++i) {
            const int row = q * 4 + i;
            const float cv   = tanhf_(cc[i] + cb);
            const float up   = ub[row * HS + ccol];
            const float hold = hf[row * HS + ccol];
            const float hn   = up * hold + (1.0f - up) * cv;
            const bool valid = (t < len_i[i]);
            const float hnext = valid ? hn : hold;
            OUT[((size_t)(b0 + row) * Tn + t) * Dn + ccol] = valid ? hn : 0.0f;
            hf[row * HS + ccol] = hnext;
            hb[row * BS + ccol] = f2bf(hnext);
        }

        // stage prefetched x/att into next buffers
        {
            short4v s; s[0] = f2bf(xpre.x); s[1] = f2bf(xpre.y);
                       s[2] = f2bf(xpre.z); s[3] = f2bf(xpre.w);
            *(short4v*)&xb[nxt][prow * BS + pcol] = s;
            if (tid < 16) abuf[nxt][tid] = apre;
        }
        barrier_lds();
    }
}

extern "C" void kernel_launch(void* const* d_in, const int* in_sizes, int n_in,
                              void* d_out, int out_size, void* d_ws, size_t ws_size,
                              hipStream_t stream) {
    (void)in_sizes; (void)n_in; (void)d_ws; (void)ws_size; (void)out_size;
    const float* X   = (const float*)d_in[0];
    const float* ATT = (const float*)d_in[1];
    const float* GK  = (const float*)d_in[2];
    const float* GB  = (const float*)d_in[3];
    const float* CK  = (const float*)d_in[4];
    const float* CB  = (const float*)d_in[5];
    const int*   SL  = (const int*)d_in[6];
    float* OUT = (float*)d_out;

    augru_kernel<<<dim3(Bn / 16), dim3(512), 0, stream>>>(X, ATT, GK, GB, CK, CB, SL, OUT);
}